// Round 16
// baseline (372.418 us; speedup 1.0000x reference)
//
#include <hip/hip_runtime.h>
#include <math.h>

typedef unsigned int u32;
typedef unsigned short u16;
using bf16x8 = __attribute__((ext_vector_type(8))) short;
using f32x4 = __attribute__((ext_vector_type(4))) float;

__device__ inline float bf_lo(u32 v) { return __uint_as_float(v << 16); }
__device__ inline float bf_hi(u32 v) { return __uint_as_float(v & 0xFFFF0000u); }
__device__ inline u16 f2bf(float f) {
    u32 u = __float_as_uint(f);
    return (u16)((u + 0x7FFFu + ((u >> 16) & 1u)) >> 16);
}
__device__ inline float bf2f(u16 h) { return __uint_as_float((u32)h << 16); }
__device__ inline float invdeg(int d) { return 1.0f / (float)(d > 1 ? d : 1); }

#define BIN_SHIFT 14  // 16384-node bins: 2MB colp window (L2-fits), 4 bins -> half the dst re-reads

// ---------------------------------------------------------------- front mega-kernel args
struct FrontArgs {
    const int *src, *dst;
    int* cur;
    u16* colp;
    int E, EB, SB;
    const float *value, *uu;
    float4* x4;
    int n, NBx4;
    const float *W3, *W4, *W9;        // packed to slots 0,1,2
    u16 *pkhi, *pklo;
    const float *W1, *W2, *b1;        // -> W12
    float* W12;
    const float *W5, *W6, *W7, *W8, *b5, *b6, *b7, *b8;
    float *Q1, *Q2, *v, *vw;
};

// blocks: [0,SB) scatter | [SB,SB+NBx4) x4 | 24 pack | 64 Q1 | 64 Q2 | 2 W12 | 1 v/vw
__global__ __launch_bounds__(256) void k_front(FrontArgs A) {
    int blk = blockIdx.x;
    int tid = threadIdx.x;
    if (blk < A.SB) {
        const int bin = blk / A.EB;
        int e = (blk - bin * A.EB) * 256 + tid;
        if (e >= A.E) return;
        int d = A.dst[e];
        if ((d >> BIN_SHIFT) != bin) return;
        int slot = atomicAdd(&A.cur[d], 1);
        if (slot < 64) A.colp[(size_t)d * 64 + slot] = (u16)A.src[e];
        return;
    }
    int pb = blk - A.SB;
    if (pb < A.NBx4) {
        int i = pb * 256 + tid;
        if (i < A.n) A.x4[i] = make_float4(A.value[i], A.uu[2 * i], A.uu[2 * i + 1], 1.0f);
        return;
    }
    pb -= A.NBx4;
    if (pb < 24) {  // pack W3,W4,W9
        const float* W = (pb < 8) ? A.W3 : (pb < 16) ? A.W4 : A.W9;
        const int l = pb >> 3;
        int g = (pb & 7) * 256 + tid;
        int ct = g >> 8;
        int rem = g & 255;
        int ks = rem >> 6;
        int lane = rem & 63;
        int kbase = ks * 32 + ((lane >> 4) << 3);
        int nn = (ct << 4) + (lane & 15);
        size_t off = ((size_t)l * 2048 + g) * 8;
#pragma unroll
        for (int j = 0; j < 8; ++j) {
            float w = W[(size_t)(kbase + j) * 128 + nn];
            u16 h = f2bf(w);
            A.pkhi[off + j] = h;
            A.pklo[off + j] = f2bf(w - bf2f(h));
        }
        return;
    }
    pb -= 24;
    if (pb < 64) {  // Q1 = W5*W6
        int idx = pb * 256 + tid;
        int r = idx >> 7, c = idx & 127;
        float s0 = 0.f, s1 = 0.f, s2 = 0.f, s3 = 0.f;
        for (int k = 0; k < 128; k += 4) {
            s0 += A.W5[r * 128 + k + 0] * A.W6[(k + 0) * 128 + c];
            s1 += A.W5[r * 128 + k + 1] * A.W6[(k + 1) * 128 + c];
            s2 += A.W5[r * 128 + k + 2] * A.W6[(k + 2) * 128 + c];
            s3 += A.W5[r * 128 + k + 3] * A.W6[(k + 3) * 128 + c];
        }
        A.Q1[idx] = (s0 + s1) + (s2 + s3);
        return;
    }
    pb -= 64;
    if (pb < 64) {  // Q2 = W7*W8
        int idx = pb * 256 + tid;
        int r = idx >> 7, c = idx & 127;
        float s0 = 0.f, s1 = 0.f, s2 = 0.f, s3 = 0.f;
        for (int k = 0; k < 128; k += 4) {
            s0 += A.W7[r * 128 + k + 0] * A.W8[(k + 0) * 128 + c];
            s1 += A.W7[r * 128 + k + 1] * A.W8[(k + 1) * 128 + c];
            s2 += A.W7[r * 128 + k + 2] * A.W8[(k + 2) * 128 + c];
            s3 += A.W7[r * 128 + k + 3] * A.W8[(k + 3) * 128 + c];
        }
        A.Q2[idx] = (s0 + s1) + (s2 + s3);
        return;
    }
    pb -= 64;
    if (pb < 2) {  // W12: rows 0..2 = W1*W2, row 3 = b1^T W2
        int idx = pb * 256 + tid;
        if (idx < 384) {
            int r = idx >> 7, c = idx & 127;
            float s = 0.f;
            for (int k = 0; k < 64; ++k) s += A.W1[r * 64 + k] * A.W2[k * 128 + c];
            A.W12[idx] = s;
        } else if (idx < 512) {
            int c = idx - 384;
            float s = 0.f;
            for (int k = 0; k < 64; ++k) s += A.b1[k] * A.W2[k * 128 + c];
            A.W12[idx] = s;
        }
        return;
    }
    // v = W6^T b5 + b6 ; vw = W8^T b7 + b8
    if (tid < 128) {
        float s = 0.f;
        for (int k = 0; k < 128; ++k) s += A.b5[k] * A.W6[k * 128 + tid];
        A.v[tid] = s + A.b6[tid];
    } else {
        int c = tid - 128;
        float s = 0.f;
        for (int k = 0; k < 128; ++k) s += A.b7[k] * A.W8[k * 128 + c];
        A.vw[c] = s + A.b8[c];
    }
}

// ---------------------------------------------------------------- stage2: pack(Q1*Q2) -> slot 3; bhat = v^T Q2 + vw
__global__ __launch_bounds__(256) void k_stage2(const float* __restrict__ Q1,
                                                const float* __restrict__ Q2,
                                                const float* __restrict__ v,
                                                const float* __restrict__ vw,
                                                u16* __restrict__ pkhi, u16* __restrict__ pklo,
                                                float* __restrict__ bhat) {
    int blk = blockIdx.x, tid = threadIdx.x;
    if (blk < 64) {
        int idx = blk * 256 + tid;
        int k = idx >> 7, c = idx & 127;
        float s0 = 0.f, s1 = 0.f, s2 = 0.f, s3 = 0.f;
        for (int m = 0; m < 128; m += 4) {
            s0 += Q1[k * 128 + m + 0] * Q2[(m + 0) * 128 + c];
            s1 += Q1[k * 128 + m + 1] * Q2[(m + 1) * 128 + c];
            s2 += Q1[k * 128 + m + 2] * Q2[(m + 2) * 128 + c];
            s3 += Q1[k * 128 + m + 3] * Q2[(m + 3) * 128 + c];
        }
        float val = (s0 + s1) + (s2 + s3);
        u16 h = f2bf(val);
        u16 l = f2bf(val - bf2f(h));
        int lane = (((k >> 3) & 3) << 4) | (c & 15);
        int ct = c >> 4, ks = k >> 5, j = k & 7;
        size_t off = ((size_t)(ct * 4 + ks) * 64 + lane) * 8 + j;
        pkhi[off] = h;
        pklo[off] = l;
    } else {
        if (tid < 128) {
            float s = 0.f;
            for (int k = 0; k < 128; ++k) s += v[k] * Q2[k * 128 + tid];
            bhat[tid] = s + vw[tid];
        }
    }
}

// ---------------------------------------------------------------- agg over fp32 [N,4] rows, 1 thread/node
__global__ __launch_bounds__(256) void k_agg4(const float4* __restrict__ X,
                                              const u16* __restrict__ colp,
                                              const int* __restrict__ deg,
                                              float4* __restrict__ out, int nNodes) {
    int n = blockIdx.x * 256 + threadIdx.x;
    if (n >= nNodes) return;
    int dfull = deg[n];
    int dg = dfull > 64 ? 64 : dfull;
    const u16* cl = colp + (size_t)n * 64;
    float a0 = 0.f, a1 = 0.f, a2 = 0.f, a3 = 0.f;
    int j = 0;
    for (; j + 8 <= dg; j += 8) {
        uint4 q = *reinterpret_cast<const uint4*>(cl + j);
        float4 v0 = X[q.x & 0xFFFFu], v1 = X[q.x >> 16];
        float4 v2 = X[q.y & 0xFFFFu], v3 = X[q.y >> 16];
        float4 v4 = X[q.z & 0xFFFFu], v5 = X[q.z >> 16];
        float4 v6 = X[q.w & 0xFFFFu], v7 = X[q.w >> 16];
        a0 += ((v0.x + v1.x) + (v2.x + v3.x)) + ((v4.x + v5.x) + (v6.x + v7.x));
        a1 += ((v0.y + v1.y) + (v2.y + v3.y)) + ((v4.y + v5.y) + (v6.y + v7.y));
        a2 += ((v0.z + v1.z) + (v2.z + v3.z)) + ((v4.z + v5.z) + (v6.z + v7.z));
        a3 += ((v0.w + v1.w) + (v2.w + v3.w)) + ((v4.w + v5.w) + (v6.w + v7.w));
    }
    for (; j < dg; ++j) {
        float4 v = X[cl[j]];
        a0 += v.x; a1 += v.y; a2 += v.z; a3 += v.w;
    }
    float iv = invdeg(dfull);
    out[n] = make_float4(a0 * iv, a1 * iv, a2 * iv, a3 * iv);
}

// ---------------------------------------------------------------- activation
template <int ACT>
__device__ inline float actf(float x) {
    if (ACT == 1) return x > 0.f ? x : 0.01f * x;
    if (ACT == 2) return 1.f / (1.f + expf(-x));
    return x;
}

// ---------------------------------------------------------------- agg4 + l2 fused
__global__ __launch_bounds__(256) void k_agg4l2(const float4* __restrict__ Y1,
                                                const u16* __restrict__ colp,
                                                const int* __restrict__ deg,
                                                const float* __restrict__ W12,
                                                const float* __restrict__ b2,
                                                u16* __restrict__ out, int nNodes) {
    int n = blockIdx.x * 256 + threadIdx.x;
    if (n >= nNodes) return;
    int dfull = deg[n];
    int dg = dfull > 64 ? 64 : dfull;
    const u16* cl = colp + (size_t)n * 64;
    float a0 = 0.f, a1 = 0.f, a2 = 0.f, a3 = 0.f;
    int j = 0;
    for (; j + 8 <= dg; j += 8) {
        uint4 q = *reinterpret_cast<const uint4*>(cl + j);
        float4 v0 = Y1[q.x & 0xFFFFu], v1 = Y1[q.x >> 16];
        float4 v2 = Y1[q.y & 0xFFFFu], v3 = Y1[q.y >> 16];
        float4 v4 = Y1[q.z & 0xFFFFu], v5 = Y1[q.z >> 16];
        float4 v6 = Y1[q.w & 0xFFFFu], v7 = Y1[q.w >> 16];
        a0 += ((v0.x + v1.x) + (v2.x + v3.x)) + ((v4.x + v5.x) + (v6.x + v7.x));
        a1 += ((v0.y + v1.y) + (v2.y + v3.y)) + ((v4.y + v5.y) + (v6.y + v7.y));
        a2 += ((v0.z + v1.z) + (v2.z + v3.z)) + ((v4.z + v5.z) + (v6.z + v7.z));
        a3 += ((v0.w + v1.w) + (v2.w + v3.w)) + ((v4.w + v5.w) + (v6.w + v7.w));
    }
    for (; j < dg; ++j) {
        float4 v = Y1[cl[j]];
        a0 += v.x; a1 += v.y; a2 += v.z; a3 += v.w;
    }
    float iv = invdeg(dfull);
    float yx = a0 * iv, yy = a1 * iv, yz = a2 * iv, yw = a3 * iv;

    u16* dst = out + (size_t)n * 128;
#pragma unroll 4
    for (int c0 = 0; c0 < 128; c0 += 8) {
        uint4 o;
        u32* ow = (u32*)&o;
#pragma unroll
        for (int h = 0; h < 4; ++h) {
            int c = c0 + 2 * h;
            float r0 = yx * W12[c] + yy * W12[128 + c] + yz * W12[256 + c] + yw * W12[384 + c] + b2[c];
            float r1 = yx * W12[c + 1] + yy * W12[128 + c + 1] + yz * W12[256 + c + 1] + yw * W12[384 + c + 1] + b2[c + 1];
            ow[h] = (u32)f2bf(actf<1>(r0)) | ((u32)f2bf(actf<1>(r1)) << 16);
        }
        *reinterpret_cast<uint4*>(dst + c0) = o;
    }
}

// ---------------------------------------------------------------- quad-load agg, 16 loads in flight: 16B/lane, 4 nodes/wave
__global__ __launch_bounds__(256) void k_aggq(const uint4* __restrict__ H4,
                                              const u16* __restrict__ colp,
                                              const int* __restrict__ deg,
                                              uint4* __restrict__ out, int nNodes) {
    const int tid = threadIdx.x;
    const int lane = tid & 63;
    const int wv = tid >> 6;
    const int g = lane >> 4;
    const int c = lane & 15;
    const int n = (blockIdx.x * 4 + wv) * 4 + g;
    const int nn = n < nNodes ? n : nNodes - 1;
    const int dfull = deg[nn];
    const int dg = dfull > 64 ? 64 : dfull;
    const u16* cl = colp + (size_t)nn * 64;

    int dgm = dg;
#pragma unroll
    for (int o = 32; o; o >>= 1) {
        int t = __shfl_xor(dgm, o, 64);
        dgm = t > dgm ? t : dgm;
    }

    float acc0 = 0.f, acc1 = 0.f, acc2 = 0.f, acc3 = 0.f;
    float acc4 = 0.f, acc5 = 0.f, acc6 = 0.f, acc7 = 0.f;

    for (int j = 0; j < dgm; j += 16) {
        uint4 qa = *reinterpret_cast<const uint4*>(cl + j);
        uint4 qb = *reinterpret_cast<const uint4*>(cl + j + 8);
        u32 qw[8] = {qa.x, qa.y, qa.z, qa.w, qb.x, qb.y, qb.z, qb.w};
        uint4 v[16];
        bool kk[16];
#pragma unroll
        for (int t = 0; t < 16; ++t) {
            int s = (t & 1) ? (int)(qw[t >> 1] >> 16) : (int)(qw[t >> 1] & 0xFFFFu);
            kk[t] = (j + t) < dg;
            if (!kk[t]) s = 0;
            v[t] = H4[(size_t)s * 16 + c];
        }
#pragma unroll
        for (int t = 0; t < 16; ++t) {
            if (kk[t]) {
                acc0 += bf_lo(v[t].x); acc1 += bf_hi(v[t].x);
                acc2 += bf_lo(v[t].y); acc3 += bf_hi(v[t].y);
                acc4 += bf_lo(v[t].z); acc5 += bf_hi(v[t].z);
                acc6 += bf_lo(v[t].w); acc7 += bf_hi(v[t].w);
            }
        }
    }

    float iv = invdeg(dfull);
    uint4 o;
    o.x = (u32)f2bf(acc0 * iv) | ((u32)f2bf(acc1 * iv) << 16);
    o.y = (u32)f2bf(acc2 * iv) | ((u32)f2bf(acc3 * iv) << 16);
    o.z = (u32)f2bf(acc4 * iv) | ((u32)f2bf(acc5 * iv) << 16);
    o.w = (u32)f2bf(acc6 * iv) | ((u32)f2bf(acc7 * iv) << 16);
    if (n < nNodes) out[(size_t)n * 16 + c] = o;
}

// ---------------------------------------------------------------- MFMA GEMM (R8-proven): bf16 [N,128] @ packed W -> bf16
template <int ACT>
__global__ __launch_bounds__(256) void k_mm(const u16* __restrict__ A,
                                            const u16* __restrict__ pkHi,
                                            const u16* __restrict__ pkLo,
                                            const float* __restrict__ B,
                                            u16* __restrict__ Y, int nNodes) {
    const int lane = threadIdx.x & 63;
    const int w = threadIdx.x >> 6;
    const int base = blockIdx.x * 64 + w * 16;
    const int m = lane & 15;
    const int kb = lane >> 4;
    int arow = base + m;
    if (arow >= nNodes) arow = nNodes - 1;

    bf16x8 aF[4];
#pragma unroll
    for (int ks = 0; ks < 4; ++ks)
        aF[ks] = *reinterpret_cast<const bf16x8*>(A + (size_t)arow * 128 + ks * 32 + kb * 8);

    const bf16x8* bh = reinterpret_cast<const bf16x8*>(pkHi);
    const bf16x8* bl = reinterpret_cast<const bf16x8*>(pkLo);

#pragma unroll
    for (int ct = 0; ct < 8; ++ct) {
        f32x4 acc = {0.f, 0.f, 0.f, 0.f};
#pragma unroll
        for (int ks = 0; ks < 4; ++ks) {
            acc = __builtin_amdgcn_mfma_f32_16x16x32_bf16(aF[ks], bh[(ct * 4 + ks) * 64 + lane], acc, 0, 0, 0);
            acc = __builtin_amdgcn_mfma_f32_16x16x32_bf16(aF[ks], bl[(ct * 4 + ks) * 64 + lane], acc, 0, 0, 0);
        }
        float bias = B[ct * 16 + m];
#pragma unroll
        for (int r = 0; r < 4; ++r) {
            int row = base + kb * 4 + r;
            if (row < nNodes)
                Y[(size_t)row * 128 + ct * 16 + m] = f2bf(actf<ACT>(acc[r] + bias));
        }
    }
}

// ---------------------------------------------------------------- L9+L10a fused: sigmoid(h9) @ W10 -> t[N]
__global__ __launch_bounds__(256) void k_mm_last(const u16* __restrict__ A,
                                                 const u16* __restrict__ pkHi,
                                                 const u16* __restrict__ pkLo,
                                                 const float* __restrict__ B,
                                                 const float* __restrict__ w10,
                                                 float* __restrict__ t, int nNodes) {
    const int lane = threadIdx.x & 63;
    const int w = threadIdx.x >> 6;
    const int base = blockIdx.x * 64 + w * 16;
    const int m = lane & 15;
    const int kb = lane >> 4;
    int arow = base + m;
    if (arow >= nNodes) arow = nNodes - 1;

    bf16x8 aF[4];
#pragma unroll
    for (int ks = 0; ks < 4; ++ks)
        aF[ks] = *reinterpret_cast<const bf16x8*>(A + (size_t)arow * 128 + ks * 32 + kb * 8);

    const bf16x8* bh = reinterpret_cast<const bf16x8*>(pkHi);
    const bf16x8* bl = reinterpret_cast<const bf16x8*>(pkLo);

    float p0 = 0.f, p1 = 0.f, p2 = 0.f, p3 = 0.f;
#pragma unroll
    for (int ct = 0; ct < 8; ++ct) {
        f32x4 acc = {0.f, 0.f, 0.f, 0.f};
#pragma unroll
        for (int ks = 0; ks < 4; ++ks) {
            acc = __builtin_amdgcn_mfma_f32_16x16x32_bf16(aF[ks], bh[(ct * 4 + ks) * 64 + lane], acc, 0, 0, 0);
            acc = __builtin_amdgcn_mfma_f32_16x16x32_bf16(aF[ks], bl[(ct * 4 + ks) * 64 + lane], acc, 0, 0, 0);
        }
        float bias = B[ct * 16 + m];
        float wv = w10[ct * 16 + m];
        p0 += wv * actf<2>(acc[0] + bias);
        p1 += wv * actf<2>(acc[1] + bias);
        p2 += wv * actf<2>(acc[2] + bias);
        p3 += wv * actf<2>(acc[3] + bias);
    }
#pragma unroll
    for (int o = 1; o < 16; o <<= 1) {
        p0 += __shfl_xor(p0, o, 64);
        p1 += __shfl_xor(p1, o, 64);
        p2 += __shfl_xor(p2, o, 64);
        p3 += __shfl_xor(p3, o, 64);
    }
    if (m == 0) {
        int r0 = base + kb * 4;
        if (r0 + 0 < nNodes) t[r0 + 0] = p0;
        if (r0 + 1 < nNodes) t[r0 + 1] = p1;
        if (r0 + 2 < nNodes) t[r0 + 2] = p2;
        if (r0 + 3 < nNodes) t[r0 + 3] = p3;
    }
}

// ---------------------------------------------------------------- L10b: out = inv * sum(t[src]) + b10
__global__ __launch_bounds__(256) void k_aggs(const float* __restrict__ t,
                                              const u16* __restrict__ colp,
                                              const int* __restrict__ deg,
                                              const float* __restrict__ B,
                                              float* __restrict__ out, int nNodes) {
    int n = blockIdx.x * 256 + threadIdx.x;
    if (n >= nNodes) return;
    int dfull = deg[n];
    int dg = dfull > 64 ? 64 : dfull;
    const u16* cl = colp + (size_t)n * 64;
    float s = 0.f;
    for (int j = 0; j < dg; ++j) s += t[cl[j]];
    out[n] = s * invdeg(dfull) + B[0];
}

// ---------------------------------------------------------------- host
extern "C" void kernel_launch(void* const* d_in, const int* in_sizes, int n_in,
                              void* d_out, int out_size, void* d_ws, size_t ws_size,
                              hipStream_t stream) {
    const float* value = (const float*)d_in[0];
    const float* u = (const float*)d_in[1];
    const int* src = (const int*)d_in[2];
    const int* dst = (const int*)d_in[3];
    const float* W[10];
    const float* b[10];
    for (int i = 0; i < 10; ++i) {
        W[i] = (const float*)d_in[4 + 2 * i];
        b[i] = (const float*)d_in[5 + 2 * i];
    }
    const int N = in_sizes[0];
    const int E = in_sizes[2];
    float* out = (float*)d_out;

    char* p = (char*)d_ws;
    auto carve = [&](size_t bytes) {
        char* r = p;
        p += (bytes + 255) & ~(size_t)255;
        return r;
    };
    int* deg = (int*)carve((size_t)N * 4);
    u16* colp = (u16*)carve((size_t)N * 64 * 2);
    float4* x4 = (float4*)carve((size_t)N * 16);
    float4* y1 = (float4*)carve((size_t)N * 16);
    u16* hA = (u16*)carve((size_t)N * 128 * 2);
    u16* hB = (u16*)carve((size_t)N * 128 * 2);
    u16* agg = (u16*)carve((size_t)N * 128 * 2);
    float* t10 = (float*)carve((size_t)N * 4);
    u16* pkhi = (u16*)carve((size_t)4 * 2048 * 8 * 2);  // slots: 0=W3,1=W4,2=W9,3=W5678
    u16* pklo = (u16*)carve((size_t)4 * 2048 * 8 * 2);
    float* Q1 = (float*)carve((size_t)128 * 128 * 4);
    float* Q2 = (float*)carve((size_t)128 * 128 * 4);
    float* vv = (float*)carve(128 * 4);
    float* vw = (float*)carve(128 * 4);
    float* bhat = (float*)carve(128 * 4);
    float* W12 = (float*)carve(512 * 4);

    const int nbins = (N + (1 << BIN_SHIFT) - 1) >> BIN_SHIFT;
    const int EB = (E + 255) / 256;
    const int SB = EB * nbins;
    const int NBx4 = (N + 255) / 256;

    hipMemsetAsync(deg, 0, (size_t)N * 4, stream);

    FrontArgs FA;
    FA.src = src; FA.dst = dst; FA.cur = deg; FA.colp = colp;
    FA.E = E; FA.EB = EB; FA.SB = SB;
    FA.value = value; FA.uu = u; FA.x4 = x4; FA.n = N; FA.NBx4 = NBx4;
    FA.W3 = W[2]; FA.W4 = W[3]; FA.W9 = W[8]; FA.pkhi = pkhi; FA.pklo = pklo;
    FA.W1 = W[0]; FA.W2 = W[1]; FA.b1 = b[0]; FA.W12 = W12;
    FA.W5 = W[4]; FA.W6 = W[5]; FA.W7 = W[6]; FA.W8 = W[7];
    FA.b5 = b[4]; FA.b6 = b[5]; FA.b7 = b[6]; FA.b8 = b[7];
    FA.Q1 = Q1; FA.Q2 = Q2; FA.v = vv; FA.vw = vw;
    k_front<<<SB + NBx4 + 24 + 64 + 64 + 2 + 1, 256, 0, stream>>>(FA);

    const size_t PK = 2048 * 8;
    k_stage2<<<65, 256, 0, stream>>>(Q1, Q2, vv, vw, pkhi + 3 * PK, pklo + 3 * PK, bhat);

    const int ga4 = (N + 255) / 256;
    const int gq = (N + 15) / 16;
    const int gg = (N + 63) / 64;
    const int gt = (N + 255) / 256;

    // L1+L2 collapsed: y1 = A([x,1]); h2 = lrelu(A(y1) @ W12 + b2)
    k_agg4<<<ga4, 256, 0, stream>>>(x4, colp, deg, y1, N);
    k_agg4l2<<<ga4, 256, 0, stream>>>(y1, colp, deg, W12, b[1], hA, N);
    // L3, L4: lrelu
    k_aggq<<<gq, 256, 0, stream>>>((const uint4*)hA, colp, deg, (uint4*)agg, N);
    k_mm<1><<<gg, 256, 0, stream>>>(agg, pkhi + 0 * PK, pklo + 0 * PK, b[2], hB, N);
    k_aggq<<<gq, 256, 0, stream>>>((const uint4*)hB, colp, deg, (uint4*)agg, N);
    k_mm<1><<<gg, 256, 0, stream>>>(agg, pkhi + 1 * PK, pklo + 1 * PK, b[3], hA, N);
    // L5-L8 collapsed: z = A^4(h4); h8 = z @ (W5W6W7W8) + bhat
    k_aggq<<<gq, 256, 0, stream>>>((const uint4*)hA, colp, deg, (uint4*)hB, N);
    k_aggq<<<gq, 256, 0, stream>>>((const uint4*)hB, colp, deg, (uint4*)hA, N);
    k_aggq<<<gq, 256, 0, stream>>>((const uint4*)hA, colp, deg, (uint4*)hB, N);
    k_aggq<<<gq, 256, 0, stream>>>((const uint4*)hB, colp, deg, (uint4*)agg, N);
    k_mm<0><<<gg, 256, 0, stream>>>(agg, pkhi + 3 * PK, pklo + 3 * PK, bhat, hA, N);
    // L9 + L10a: sigmoid + dot W10 -> t
    k_aggq<<<gq, 256, 0, stream>>>((const uint4*)hA, colp, deg, (uint4*)agg, N);
    k_mm_last<<<gg, 256, 0, stream>>>(agg, pkhi + 2 * PK, pklo + 2 * PK, b[8], W[9], t10, N);
    // L10b
    k_aggs<<<gt, 256, 0, stream>>>(t10, colp, deg, b[9], out, N);
}

// Round 17
// 366.409 us; speedup vs baseline: 1.0164x; 1.0164x over previous
//
#include <hip/hip_runtime.h>
#include <math.h>

typedef unsigned int u32;
typedef unsigned short u16;
using bf16x8 = __attribute__((ext_vector_type(8))) short;
using f32x4 = __attribute__((ext_vector_type(4))) float;

__device__ inline float bf_lo(u32 v) { return __uint_as_float(v << 16); }
__device__ inline float bf_hi(u32 v) { return __uint_as_float(v & 0xFFFF0000u); }
__device__ inline u16 f2bf(float f) {
    u32 u = __float_as_uint(f);
    return (u16)((u + 0x7FFFu + ((u >> 16) & 1u)) >> 16);
}
__device__ inline float bf2f(u16 h) { return __uint_as_float((u32)h << 16); }
__device__ inline float invdeg(int d) { return 1.0f / (float)(d > 1 ? d : 1); }

#define BIN_SHIFT 13

struct W3p { const float* p[3]; };

// ---------------------------------------------------------------- front: bin-seq scatter + x4 build (w=1) + pack W3,W4,W9
__global__ __launch_bounds__(256) void k_front(const int* __restrict__ src,
                                               const int* __restrict__ dst,
                                               int* __restrict__ cur,
                                               u16* __restrict__ colp,
                                               int E, int EB, int SB,
                                               const float* __restrict__ value,
                                               const float* __restrict__ u,
                                               float4* __restrict__ x4, int n, int NBx4,
                                               W3p wp,
                                               u16* __restrict__ hi128, u16* __restrict__ lo128) {
    int blk = blockIdx.x;
    if (blk < SB) {
        const int bin = blk / EB;
        int e = (blk - bin * EB) * 256 + threadIdx.x;
        if (e >= E) return;
        int d = dst[e];
        if ((d >> BIN_SHIFT) != bin) return;
        int slot = atomicAdd(&cur[d], 1);
        if (slot < 64) colp[(size_t)d * 64 + slot] = (u16)src[e];
        return;
    }
    int pb = blk - SB;
    if (pb < NBx4) {
        int i = pb * 256 + threadIdx.x;
        if (i < n) x4[i] = make_float4(value[i], u[2 * i], u[2 * i + 1], 1.0f);
        return;
    }
    pb -= NBx4;
    // pack 3 layers (W3, W4, W9): pb in [0,24)
    const int l = pb >> 3;
    const float* W = wp.p[l];
    int g = (pb & 7) * 256 + threadIdx.x;  // 0..2047
    int ct = g >> 8;
    int rem = g & 255;
    int ks = rem >> 6;
    int lane = rem & 63;
    int kbase = ks * 32 + ((lane >> 4) << 3);
    int nn = (ct << 4) + (lane & 15);
    size_t off = ((size_t)l * 2048 + g) * 8;
#pragma unroll
    for (int j = 0; j < 8; ++j) {
        float w = W[(size_t)(kbase + j) * 128 + nn];
        u16 h = f2bf(w);
        hi128[off + j] = h;
        lo128[off + j] = f2bf(w - bf2f(h));
    }
}

// ---------------------------------------------------------------- weight-product stages (fp32)
__global__ __launch_bounds__(256) void k_stageA(const float* __restrict__ W7, const float* __restrict__ W8,
                                                const float* __restrict__ b7, const float* __restrict__ b8,
                                                const float* __restrict__ W1, const float* __restrict__ W2,
                                                const float* __restrict__ b1,
                                                float* __restrict__ P1, float* __restrict__ bp1,
                                                float* __restrict__ W12) {
    int blk = blockIdx.x, tid = threadIdx.x;
    if (blk < 64) {
        int idx = blk * 256 + tid;
        int r = idx >> 7, c = idx & 127;
        float s0 = 0.f, s1 = 0.f, s2 = 0.f, s3 = 0.f;
        for (int k = 0; k < 128; k += 4) {
            s0 += W7[r * 128 + k + 0] * W8[(k + 0) * 128 + c];
            s1 += W7[r * 128 + k + 1] * W8[(k + 1) * 128 + c];
            s2 += W7[r * 128 + k + 2] * W8[(k + 2) * 128 + c];
            s3 += W7[r * 128 + k + 3] * W8[(k + 3) * 128 + c];
        }
        P1[idx] = (s0 + s1) + (s2 + s3);
    } else if (blk < 66) {
        int idx = (blk - 64) * 256 + tid;
        if (idx < 384) {
            int r = idx >> 7, c = idx & 127;
            float s = 0.f;
            for (int k = 0; k < 64; ++k) s += W1[r * 64 + k] * W2[k * 128 + c];
            W12[idx] = s;
        }
    } else if (blk == 66) {
        if (tid < 128) {
            float s = 0.f;
            for (int k = 0; k < 64; ++k) s += b1[k] * W2[k * 128 + tid];
            W12[384 + tid] = s;
        }
    } else {
        if (tid < 128) {
            float s = 0.f;
            for (int k = 0; k < 128; ++k) s += b7[k] * W8[k * 128 + tid];
            bp1[tid] = s + b8[tid];
        }
    }
}

__global__ __launch_bounds__(256) void k_stageB(const float* __restrict__ W6,
                                                const float* __restrict__ b6,
                                                const float* __restrict__ P1,
                                                const float* __restrict__ bp1,
                                                float* __restrict__ P2, float* __restrict__ bp2) {
    int blk = blockIdx.x, tid = threadIdx.x;
    if (blk < 64) {
        int idx = blk * 256 + tid;
        int r = idx >> 7, c = idx & 127;
        float s0 = 0.f, s1 = 0.f, s2 = 0.f, s3 = 0.f;
        for (int k = 0; k < 128; k += 4) {
            s0 += W6[r * 128 + k + 0] * P1[(k + 0) * 128 + c];
            s1 += W6[r * 128 + k + 1] * P1[(k + 1) * 128 + c];
            s2 += W6[r * 128 + k + 2] * P1[(k + 2) * 128 + c];
            s3 += W6[r * 128 + k + 3] * P1[(k + 3) * 128 + c];
        }
        P2[idx] = (s0 + s1) + (s2 + s3);
    } else {
        if (tid < 128) {
            float s = 0.f;
            for (int k = 0; k < 128; ++k) s += b6[k] * P1[k * 128 + tid];
            bp2[tid] = s + bp1[tid];
        }
    }
}

__global__ __launch_bounds__(256) void k_stageC(const float* __restrict__ W5,
                                                const float* __restrict__ b5,
                                                const float* __restrict__ P2,
                                                const float* __restrict__ bp2,
                                                u16* __restrict__ pkhi, u16* __restrict__ pklo,
                                                float* __restrict__ bhat) {
    int blk = blockIdx.x, tid = threadIdx.x;
    if (blk < 64) {
        int idx = blk * 256 + tid;
        int k = idx >> 7, c = idx & 127;
        float s0 = 0.f, s1 = 0.f, s2 = 0.f, s3 = 0.f;
        for (int m = 0; m < 128; m += 4) {
            s0 += W5[k * 128 + m + 0] * P2[(m + 0) * 128 + c];
            s1 += W5[k * 128 + m + 1] * P2[(m + 1) * 128 + c];
            s2 += W5[k * 128 + m + 2] * P2[(m + 2) * 128 + c];
            s3 += W5[k * 128 + m + 3] * P2[(m + 3) * 128 + c];
        }
        float val = (s0 + s1) + (s2 + s3);
        u16 h = f2bf(val);
        u16 l = f2bf(val - bf2f(h));
        int lane = (((k >> 3) & 3) << 4) | (c & 15);
        int ct = c >> 4, ks = k >> 5, j = k & 7;
        size_t off = ((size_t)(ct * 4 + ks) * 64 + lane) * 8 + j;
        pkhi[off] = h;
        pklo[off] = l;
    } else {
        if (tid < 128) {
            float s = 0.f;
            for (int k = 0; k < 128; ++k) s += b5[k] * P2[k * 128 + tid];
            bhat[tid] = s + bp2[tid];
        }
    }
}

// ---------------------------------------------------------------- agg over fp32 [N,4] rows (16B), 1 thread/node
__global__ __launch_bounds__(256) void k_agg4(const float4* __restrict__ X,
                                              const u16* __restrict__ colp,
                                              const int* __restrict__ deg,
                                              float4* __restrict__ out, int nNodes) {
    int n = blockIdx.x * 256 + threadIdx.x;
    if (n >= nNodes) return;
    int dfull = deg[n];
    int dg = dfull > 64 ? 64 : dfull;
    const u16* cl = colp + (size_t)n * 64;
    float a0 = 0.f, a1 = 0.f, a2 = 0.f, a3 = 0.f;
    int j = 0;
    for (; j + 8 <= dg; j += 8) {
        uint4 q = *reinterpret_cast<const uint4*>(cl + j);
        float4 v0 = X[q.x & 0xFFFFu], v1 = X[q.x >> 16];
        float4 v2 = X[q.y & 0xFFFFu], v3 = X[q.y >> 16];
        float4 v4 = X[q.z & 0xFFFFu], v5 = X[q.z >> 16];
        float4 v6 = X[q.w & 0xFFFFu], v7 = X[q.w >> 16];
        a0 += ((v0.x + v1.x) + (v2.x + v3.x)) + ((v4.x + v5.x) + (v6.x + v7.x));
        a1 += ((v0.y + v1.y) + (v2.y + v3.y)) + ((v4.y + v5.y) + (v6.y + v7.y));
        a2 += ((v0.z + v1.z) + (v2.z + v3.z)) + ((v4.z + v5.z) + (v6.z + v7.z));
        a3 += ((v0.w + v1.w) + (v2.w + v3.w)) + ((v4.w + v5.w) + (v6.w + v7.w));
    }
    for (; j < dg; ++j) {
        float4 v = X[cl[j]];
        a0 += v.x; a1 += v.y; a2 += v.z; a3 += v.w;
    }
    float iv = invdeg(dfull);
    out[n] = make_float4(a0 * iv, a1 * iv, a2 * iv, a3 * iv);
}

// ---------------------------------------------------------------- activation
template <int ACT>
__device__ inline float actf(float x) {
    if (ACT == 1) return x > 0.f ? x : 0.01f * x;
    if (ACT == 2) return 1.f / (1.f + expf(-x));
    return x;
}

// ---------------------------------------------------------------- L1+L2 collapsed: h2 = lrelu(y2 @ W12[4x128] + b2) -> bf16
__global__ __launch_bounds__(256) void k_l2(const float4* __restrict__ y2,
                                            const float* __restrict__ W12,
                                            const float* __restrict__ b2,
                                            u16* __restrict__ out, int nNodes) {
    int node = blockIdx.x * 2 + (threadIdx.x >> 7);
    int c = threadIdx.x & 127;
    if (node >= nNodes) return;
    float4 y = y2[node];
    float r = y.x * W12[c] + y.y * W12[128 + c] + y.z * W12[256 + c] + y.w * W12[384 + c] + b2[c];
    out[(size_t)node * 128 + c] = f2bf(actf<1>(r));
}

// ---------------------------------------------------------------- quad-load agg (R13-proven): 16B/lane, 4 nodes/wave, unroll-8
__global__ __launch_bounds__(256) void k_aggq(const uint4* __restrict__ H4,
                                              const u16* __restrict__ colp,
                                              const int* __restrict__ deg,
                                              uint4* __restrict__ out, int nNodes) {
    const int tid = threadIdx.x;
    const int lane = tid & 63;
    const int wv = tid >> 6;
    const int g = lane >> 4;
    const int c = lane & 15;
    const int n = (blockIdx.x * 4 + wv) * 4 + g;
    const int nn = n < nNodes ? n : nNodes - 1;
    const int dfull = deg[nn];
    const int dg = dfull > 64 ? 64 : dfull;
    const u16* cl = colp + (size_t)nn * 64;

    int dgm = dg;
#pragma unroll
    for (int o = 32; o; o >>= 1) {
        int t = __shfl_xor(dgm, o, 64);
        dgm = t > dgm ? t : dgm;
    }

    float acc0 = 0.f, acc1 = 0.f, acc2 = 0.f, acc3 = 0.f;
    float acc4 = 0.f, acc5 = 0.f, acc6 = 0.f, acc7 = 0.f;

    for (int j = 0; j < dgm; j += 8) {
        uint4 iv4 = *reinterpret_cast<const uint4*>(cl + j);
        int s0 = (int)(iv4.x & 0xFFFFu), s1 = (int)(iv4.x >> 16);
        int s2 = (int)(iv4.y & 0xFFFFu), s3 = (int)(iv4.y >> 16);
        int s4 = (int)(iv4.z & 0xFFFFu), s5 = (int)(iv4.z >> 16);
        int s6 = (int)(iv4.w & 0xFFFFu), s7 = (int)(iv4.w >> 16);
        bool k0 = j + 0 < dg, k1 = j + 1 < dg, k2 = j + 2 < dg, k3 = j + 3 < dg;
        bool k4 = j + 4 < dg, k5 = j + 5 < dg, k6 = j + 6 < dg, k7 = j + 7 < dg;
        if (!k0) s0 = 0; if (!k1) s1 = 0; if (!k2) s2 = 0; if (!k3) s3 = 0;
        if (!k4) s4 = 0; if (!k5) s5 = 0; if (!k6) s6 = 0; if (!k7) s7 = 0;
        uint4 v0 = H4[(size_t)s0 * 16 + c];
        uint4 v1 = H4[(size_t)s1 * 16 + c];
        uint4 v2 = H4[(size_t)s2 * 16 + c];
        uint4 v3 = H4[(size_t)s3 * 16 + c];
        uint4 v4 = H4[(size_t)s4 * 16 + c];
        uint4 v5 = H4[(size_t)s5 * 16 + c];
        uint4 v6 = H4[(size_t)s6 * 16 + c];
        uint4 v7 = H4[(size_t)s7 * 16 + c];
        if (k0) { acc0 += bf_lo(v0.x); acc1 += bf_hi(v0.x); acc2 += bf_lo(v0.y); acc3 += bf_hi(v0.y);
                  acc4 += bf_lo(v0.z); acc5 += bf_hi(v0.z); acc6 += bf_lo(v0.w); acc7 += bf_hi(v0.w); }
        if (k1) { acc0 += bf_lo(v1.x); acc1 += bf_hi(v1.x); acc2 += bf_lo(v1.y); acc3 += bf_hi(v1.y);
                  acc4 += bf_lo(v1.z); acc5 += bf_hi(v1.z); acc6 += bf_lo(v1.w); acc7 += bf_hi(v1.w); }
        if (k2) { acc0 += bf_lo(v2.x); acc1 += bf_hi(v2.x); acc2 += bf_lo(v2.y); acc3 += bf_hi(v2.y);
                  acc4 += bf_lo(v2.z); acc5 += bf_hi(v2.z); acc6 += bf_lo(v2.w); acc7 += bf_hi(v2.w); }
        if (k3) { acc0 += bf_lo(v3.x); acc1 += bf_hi(v3.x); acc2 += bf_lo(v3.y); acc3 += bf_hi(v3.y);
                  acc4 += bf_lo(v3.z); acc5 += bf_hi(v3.z); acc6 += bf_lo(v3.w); acc7 += bf_hi(v3.w); }
        if (k4) { acc0 += bf_lo(v4.x); acc1 += bf_hi(v4.x); acc2 += bf_lo(v4.y); acc3 += bf_hi(v4.y);
                  acc4 += bf_lo(v4.z); acc5 += bf_hi(v4.z); acc6 += bf_lo(v4.w); acc7 += bf_hi(v4.w); }
        if (k5) { acc0 += bf_lo(v5.x); acc1 += bf_hi(v5.x); acc2 += bf_lo(v5.y); acc3 += bf_hi(v5.y);
                  acc4 += bf_lo(v5.z); acc5 += bf_hi(v5.z); acc6 += bf_lo(v5.w); acc7 += bf_hi(v5.w); }
        if (k6) { acc0 += bf_lo(v6.x); acc1 += bf_hi(v6.x); acc2 += bf_lo(v6.y); acc3 += bf_hi(v6.y);
                  acc4 += bf_lo(v6.z); acc5 += bf_hi(v6.z); acc6 += bf_lo(v6.w); acc7 += bf_hi(v6.w); }
        if (k7) { acc0 += bf_lo(v7.x); acc1 += bf_hi(v7.x); acc2 += bf_lo(v7.y); acc3 += bf_hi(v7.y);
                  acc4 += bf_lo(v7.z); acc5 += bf_hi(v7.z); acc6 += bf_lo(v7.w); acc7 += bf_hi(v7.w); }
    }

    float iv = invdeg(dfull);
    uint4 o;
    o.x = (u32)f2bf(acc0 * iv) | ((u32)f2bf(acc1 * iv) << 16);
    o.y = (u32)f2bf(acc2 * iv) | ((u32)f2bf(acc3 * iv) << 16);
    o.z = (u32)f2bf(acc4 * iv) | ((u32)f2bf(acc5 * iv) << 16);
    o.w = (u32)f2bf(acc6 * iv) | ((u32)f2bf(acc7 * iv) << 16);
    if (n < nNodes) out[(size_t)n * 16 + c] = o;
}

// ---------------------------------------------------------------- MFMA GEMM (R8-proven): bf16 [N,128] @ packed W -> bf16
template <int ACT>
__global__ __launch_bounds__(256) void k_mm(const u16* __restrict__ A,
                                            const u16* __restrict__ pkHi,
                                            const u16* __restrict__ pkLo,
                                            const float* __restrict__ B,
                                            u16* __restrict__ Y, int nNodes) {
    const int lane = threadIdx.x & 63;
    const int w = threadIdx.x >> 6;
    const int base = blockIdx.x * 64 + w * 16;
    const int m = lane & 15;
    const int kb = lane >> 4;
    int arow = base + m;
    if (arow >= nNodes) arow = nNodes - 1;

    bf16x8 aF[4];
#pragma unroll
    for (int ks = 0; ks < 4; ++ks)
        aF[ks] = *reinterpret_cast<const bf16x8*>(A + (size_t)arow * 128 + ks * 32 + kb * 8);

    const bf16x8* bh = reinterpret_cast<const bf16x8*>(pkHi);
    const bf16x8* bl = reinterpret_cast<const bf16x8*>(pkLo);

#pragma unroll
    for (int ct = 0; ct < 8; ++ct) {
        f32x4 acc = {0.f, 0.f, 0.f, 0.f};
#pragma unroll
        for (int ks = 0; ks < 4; ++ks) {
            acc = __builtin_amdgcn_mfma_f32_16x16x32_bf16(aF[ks], bh[(ct * 4 + ks) * 64 + lane], acc, 0, 0, 0);
            acc = __builtin_amdgcn_mfma_f32_16x16x32_bf16(aF[ks], bl[(ct * 4 + ks) * 64 + lane], acc, 0, 0, 0);
        }
        float bias = B[ct * 16 + m];
#pragma unroll
        for (int r = 0; r < 4; ++r) {
            int row = base + kb * 4 + r;
            if (row < nNodes)
                Y[(size_t)row * 128 + ct * 16 + m] = f2bf(actf<ACT>(acc[r] + bias));
        }
    }
}

// ---------------------------------------------------------------- L9+L10a fused: sigmoid(h9) @ W10 -> t[N]
__global__ __launch_bounds__(256) void k_mm_last(const u16* __restrict__ A,
                                                 const u16* __restrict__ pkHi,
                                                 const u16* __restrict__ pkLo,
                                                 const float* __restrict__ B,
                                                 const float* __restrict__ w10,
                                                 float* __restrict__ t, int nNodes) {
    const int lane = threadIdx.x & 63;
    const int w = threadIdx.x >> 6;
    const int base = blockIdx.x * 64 + w * 16;
    const int m = lane & 15;
    const int kb = lane >> 4;
    int arow = base + m;
    if (arow >= nNodes) arow = nNodes - 1;

    bf16x8 aF[4];
#pragma unroll
    for (int ks = 0; ks < 4; ++ks)
        aF[ks] = *reinterpret_cast<const bf16x8*>(A + (size_t)arow * 128 + ks * 32 + kb * 8);

    const bf16x8* bh = reinterpret_cast<const bf16x8*>(pkHi);
    const bf16x8* bl = reinterpret_cast<const bf16x8*>(pkLo);

    float p0 = 0.f, p1 = 0.f, p2 = 0.f, p3 = 0.f;
#pragma unroll
    for (int ct = 0; ct < 8; ++ct) {
        f32x4 acc = {0.f, 0.f, 0.f, 0.f};
#pragma unroll
        for (int ks = 0; ks < 4; ++ks) {
            acc = __builtin_amdgcn_mfma_f32_16x16x32_bf16(aF[ks], bh[(ct * 4 + ks) * 64 + lane], acc, 0, 0, 0);
            acc = __builtin_amdgcn_mfma_f32_16x16x32_bf16(aF[ks], bl[(ct * 4 + ks) * 64 + lane], acc, 0, 0, 0);
        }
        float bias = B[ct * 16 + m];
        float wv = w10[ct * 16 + m];
        p0 += wv * actf<2>(acc[0] + bias);
        p1 += wv * actf<2>(acc[1] + bias);
        p2 += wv * actf<2>(acc[2] + bias);
        p3 += wv * actf<2>(acc[3] + bias);
    }
#pragma unroll
    for (int o = 1; o < 16; o <<= 1) {
        p0 += __shfl_xor(p0, o, 64);
        p1 += __shfl_xor(p1, o, 64);
        p2 += __shfl_xor(p2, o, 64);
        p3 += __shfl_xor(p3, o, 64);
    }
    if (m == 0) {
        int r0 = base + kb * 4;
        if (r0 + 0 < nNodes) t[r0 + 0] = p0;
        if (r0 + 1 < nNodes) t[r0 + 1] = p1;
        if (r0 + 2 < nNodes) t[r0 + 2] = p2;
        if (r0 + 3 < nNodes) t[r0 + 3] = p3;
    }
}

// ---------------------------------------------------------------- L10b: out = inv * sum(t[src]) + b10
__global__ __launch_bounds__(256) void k_aggs(const float* __restrict__ t,
                                              const u16* __restrict__ colp,
                                              const int* __restrict__ deg,
                                              const float* __restrict__ B,
                                              float* __restrict__ out, int nNodes) {
    int n = blockIdx.x * 256 + threadIdx.x;
    if (n >= nNodes) return;
    int dfull = deg[n];
    int dg = dfull > 64 ? 64 : dfull;
    const u16* cl = colp + (size_t)n * 64;
    float s = 0.f;
    for (int j = 0; j < dg; ++j) s += t[cl[j]];
    out[n] = s * invdeg(dfull) + B[0];
}

// ---------------------------------------------------------------- host
extern "C" void kernel_launch(void* const* d_in, const int* in_sizes, int n_in,
                              void* d_out, int out_size, void* d_ws, size_t ws_size,
                              hipStream_t stream) {
    const float* value = (const float*)d_in[0];
    const float* u = (const float*)d_in[1];
    const int* src = (const int*)d_in[2];
    const int* dst = (const int*)d_in[3];
    const float* W[10];
    const float* b[10];
    for (int i = 0; i < 10; ++i) {
        W[i] = (const float*)d_in[4 + 2 * i];
        b[i] = (const float*)d_in[5 + 2 * i];
    }
    const int N = in_sizes[0];
    const int E = in_sizes[2];
    float* out = (float*)d_out;

    char* p = (char*)d_ws;
    auto carve = [&](size_t bytes) {
        char* r = p;
        p += (bytes + 255) & ~(size_t)255;
        return r;
    };
    int* deg = (int*)carve((size_t)N * 4);
    u16* colp = (u16*)carve((size_t)N * 64 * 2);
    float4* x4 = (float4*)carve((size_t)N * 16);
    float4* y1 = (float4*)carve((size_t)N * 16);
    float4* y2 = (float4*)carve((size_t)N * 16);
    u16* hA = (u16*)carve((size_t)N * 128 * 2);
    u16* hB = (u16*)carve((size_t)N * 128 * 2);
    u16* agg = (u16*)carve((size_t)N * 128 * 2);
    float* t10 = (float*)carve((size_t)N * 4);
    u16* pkhi = (u16*)carve((size_t)4 * 2048 * 8 * 2);  // slots: 0=W3,1=W4,2=W9,3=W5678
    u16* pklo = (u16*)carve((size_t)4 * 2048 * 8 * 2);
    float* P1 = (float*)carve((size_t)128 * 128 * 4);
    float* P2 = (float*)carve((size_t)128 * 128 * 4);
    float* bp1 = (float*)carve(128 * 4);
    float* bp2 = (float*)carve(128 * 4);
    float* bhat = (float*)carve(128 * 4);
    float* W12 = (float*)carve(512 * 4);

    const int nbins = (N + (1 << BIN_SHIFT) - 1) >> BIN_SHIFT;
    const int EB = (E + 255) / 256;
    const int SB = EB * nbins;
    const int NBx4 = (N + 255) / 256;

    hipMemsetAsync(deg, 0, (size_t)N * 4, stream);

    W3p wp;
    wp.p[0] = W[2];  // W3
    wp.p[1] = W[3];  // W4
    wp.p[2] = W[8];  // W9
    k_front<<<SB + NBx4 + 24, 256, 0, stream>>>(src, dst, deg, colp, E, EB, SB,
                                                value, u, x4, N, NBx4, wp, pkhi, pklo);
    k_stageA<<<68, 256, 0, stream>>>(W[6], W[7], b[6], b[7], W[0], W[1], b[0], P1, bp1, W12);
    k_stageB<<<65, 256, 0, stream>>>(W[5], b[5], P1, bp1, P2, bp2);
    const size_t PK = 2048 * 8;
    k_stageC<<<65, 256, 0, stream>>>(W[4], b[4], P2, bp2, pkhi + 3 * PK, pklo + 3 * PK, bhat);

    const int ga4 = (N + 255) / 256;
    const int gl2 = (N + 1) / 2;
    const int gq = (N + 15) / 16;
    const int gg = (N + 63) / 64;
    const int gt = (N + 255) / 256;

    // L1+L2 collapsed: y2 = A^2([x,1]); h2 = lrelu(y2 @ W12 + b2)
    k_agg4<<<ga4, 256, 0, stream>>>(x4, colp, deg, y1, N);
    k_agg4<<<ga4, 256, 0, stream>>>(y1, colp, deg, y2, N);
    k_l2<<<gl2, 256, 0, stream>>>(y2, W12, b[1], hA, N);
    // L3, L4: lrelu
    k_aggq<<<gq, 256, 0, stream>>>((const uint4*)hA, colp, deg, (uint4*)agg, N);
    k_mm<1><<<gg, 256, 0, stream>>>(agg, pkhi + 0 * PK, pklo + 0 * PK, b[2], hB, N);
    k_aggq<<<gq, 256, 0, stream>>>((const uint4*)hB, colp, deg, (uint4*)agg, N);
    k_mm<1><<<gg, 256, 0, stream>>>(agg, pkhi + 1 * PK, pklo + 1 * PK, b[3], hA, N);
    // L5-L8 collapsed: z = A^4(h4); h8 = z @ (W5W6W7W8) + bhat
    k_aggq<<<gq, 256, 0, stream>>>((const uint4*)hA, colp, deg, (uint4*)hB, N);
    k_aggq<<<gq, 256, 0, stream>>>((const uint4*)hB, colp, deg, (uint4*)hA, N);
    k_aggq<<<gq, 256, 0, stream>>>((const uint4*)hA, colp, deg, (uint4*)hB, N);
    k_aggq<<<gq, 256, 0, stream>>>((const uint4*)hB, colp, deg, (uint4*)agg, N);
    k_mm<0><<<gg, 256, 0, stream>>>(agg, pkhi + 3 * PK, pklo + 3 * PK, bhat, hA, N);
    // L9 + L10a: sigmoid + dot W10 -> t
    k_aggq<<<gq, 256, 0, stream>>>((const uint4*)hA, colp, deg, (uint4*)agg, N);
    k_mm_last<<<gg, 256, 0, stream>>>(agg, pkhi + 2 * PK, pklo + 2 * PK, b[8], W[9], t10, N);
    // L10b
    k_aggs<<<gt, 256, 0, stream>>>(t10, colp, deg, b[9], out, N);
}